// Round 2
// baseline (1109.321 us; speedup 1.0000x reference)
//
#include <hip/hip_runtime.h>
#include <hip/hip_bf16.h>

// ---------- types ----------
typedef __attribute__((ext_vector_type(8))) short short8;
typedef __attribute__((ext_vector_type(4))) float f32x4;

static __device__ __forceinline__ unsigned short f2bf(float x) {
  union { __hip_bfloat16 h; unsigned short u; } cv;
  cv.h = __float2bfloat16(x);
  return cv.u;
}

// ---------- cast fp32 -> bf16, up to 4 concatenated segments ----------
__global__ void cast4_kernel(const float* __restrict__ s0, long n0,
                             const float* __restrict__ s1, long n1,
                             const float* __restrict__ s2, long n2,
                             const float* __restrict__ s3, long n3,
                             unsigned short* __restrict__ dst) {
  long N4 = (n0 + n1 + n2 + n3) >> 2;  // all segment sizes are multiples of 4
  for (long i = blockIdx.x * (long)blockDim.x + threadIdx.x; i < N4;
       i += (long)gridDim.x * blockDim.x) {
    long e = i << 2;
    const float* s; long j = e;
    if (j < n0) s = s0;
    else { j -= n0; if (j < n1) s = s1;
      else { j -= n1; if (j < n2) s = s2;
        else { j -= n2; s = s3; } } }
    float4 v = *reinterpret_cast<const float4*>(s + j);
    ushort4 o;
    o.x = f2bf(v.x); o.y = f2bf(v.y); o.z = f2bf(v.z); o.w = f2bf(v.w);
    *reinterpret_cast<ushort4*>(dst + e) = o;
  }
}

// ---------- generic NT bf16 MFMA GEMM ----------
// C[m,n] = alpha * sum_inner sum_k A[m,k] * B[n,k]
// A row stride = K, B row stride = K, C row stride = N.
// batch z: b = z / Hdiv, h = z % Hdiv; A += b*sAb + h*sAh; B += b*sBb + h*sBh;
// C += z*sC. Inner loop (nInner) advances A by iA, B by iB (head accumulation).
// OUT_F32: 1 -> fp32 C, 0 -> bf16 C. DO_STATS: atomicAdd(sum,sumsq) to stats[z*2].
template<int OUT_F32, int DO_STATS>
__global__ __launch_bounds__(256)
void gemm_nt(const unsigned short* __restrict__ A,
             const unsigned short* __restrict__ B,
             void* __restrict__ Cp,
             int M, int N, int K, int Hdiv,
             long sAb, long sAh, long sBb, long sBh, long sC,
             int nInner, long iA, long iB, float alpha,
             float* __restrict__ stats) {
  __shared__ unsigned short As[64 * 32];
  __shared__ unsigned short Bs[64 * 32];
  __shared__ float red[8];

  int z = blockIdx.z;
  int b = z / Hdiv, h = z % Hdiv;
  const unsigned short* Ab = A + (long)b * sAb + (long)h * sAh;
  const unsigned short* Bb = B + (long)b * sBb + (long)h * sBh;
  int m0 = blockIdx.y * 64, n0 = blockIdx.x * 64;
  int t = threadIdx.x;
  int lane = t & 63, wave = t >> 6;
  int wm = (wave >> 1) * 32, wn = (wave & 1) * 32;
  int l15 = lane & 15, q = lane >> 4;
  int arow = t >> 2, acol = (t & 3) * 8;

  f32x4 acc[2][2] = {};

  for (int it = 0; it < nInner; ++it) {
    const unsigned short* ga0 = Ab + (long)it * iA + (long)(m0 + arow) * K + acol;
    const unsigned short* gb0 = Bb + (long)it * iB + (long)(n0 + arow) * K + acol;
    for (int k0 = 0; k0 < K; k0 += 32) {
      __syncthreads();  // protect LDS from overwrite while still being read
      __builtin_amdgcn_global_load_lds(
          (const __attribute__((address_space(1))) void*)(ga0 + k0),
          (__attribute__((address_space(3))) void*)(As + t * 8), 16, 0, 0);
      __builtin_amdgcn_global_load_lds(
          (const __attribute__((address_space(1))) void*)(gb0 + k0),
          (__attribute__((address_space(3))) void*)(Bs + t * 8), 16, 0, 0);
      __syncthreads();  // drains vmcnt: staged data visible
      short8 a0 = *reinterpret_cast<const short8*>(As + (wm + l15) * 32 + q * 8);
      short8 a1 = *reinterpret_cast<const short8*>(As + (wm + 16 + l15) * 32 + q * 8);
      short8 b0 = *reinterpret_cast<const short8*>(Bs + (wn + l15) * 32 + q * 8);
      short8 b1 = *reinterpret_cast<const short8*>(Bs + (wn + 16 + l15) * 32 + q * 8);
      acc[0][0] = __builtin_amdgcn_mfma_f32_16x16x32_bf16(a0, b0, acc[0][0], 0, 0, 0);
      acc[0][1] = __builtin_amdgcn_mfma_f32_16x16x32_bf16(a0, b1, acc[0][1], 0, 0, 0);
      acc[1][0] = __builtin_amdgcn_mfma_f32_16x16x32_bf16(a1, b0, acc[1][0], 0, 0, 0);
      acc[1][1] = __builtin_amdgcn_mfma_f32_16x16x32_bf16(a1, b1, acc[1][1], 0, 0, 0);
    }
  }

  long cbase = (long)z * sC;
  float ssum = 0.f, ssq = 0.f;
#pragma unroll
  for (int mt = 0; mt < 2; ++mt)
#pragma unroll
    for (int nt = 0; nt < 2; ++nt)
#pragma unroll
      for (int r = 0; r < 4; ++r) {
        float v = acc[mt][nt][r] * alpha;
        int rg = m0 + wm + mt * 16 + q * 4 + r;
        int cg = n0 + wn + nt * 16 + l15;
        long idx = cbase + (long)rg * N + cg;
        if (OUT_F32) ((float*)Cp)[idx] = v;
        else ((unsigned short*)Cp)[idx] = f2bf(v);
        if (DO_STATS) { ssum += v; ssq += v * v; }
      }

  if (DO_STATS) {
#pragma unroll
    for (int o = 32; o; o >>= 1) {
      ssum += __shfl_down(ssum, o, 64);
      ssq  += __shfl_down(ssq,  o, 64);
    }
    if (lane == 0) { red[wave] = ssum; red[wave + 4] = ssq; }
    __syncthreads();
    if (t == 0) {
      atomicAdd(stats + (long)z * 2,     red[0] + red[1] + red[2] + red[3]);
      atomicAdd(stats + (long)z * 2 + 1, red[4] + red[5] + red[6] + red[7]);
    }
  }
}

// ---------- instance-norm + softmax over KV=960, bf16 probs out ----------
__global__ __launch_bounds__(256)
void norm_softmax_k(const float* __restrict__ S, unsigned short* __restrict__ P,
                    const float* __restrict__ stats, int C, float invCnt) {
  const int KV = 960;
  long row = blockIdx.x;            // 0 .. 32*C-1  (bh*C + c)
  int bh = (int)(row / C);
  const float* s = S + row * KV;
  float m1 = stats[bh * 2 + 0] * invCnt;
  float m2 = stats[bh * 2 + 1] * invCnt;
  float rsig = rsqrtf(m2 - m1 * m1 + 1e-5f);
  int t = threadIdx.x;
  float e[4]; float acc = 0.f;
#pragma unroll
  for (int j = 0; j < 4; ++j) {
    int i = t + j * 256;
    if (i < KV) { e[j] = __expf((s[i] - m1) * rsig); acc += e[j]; }
    else e[j] = 0.f;
  }
#pragma unroll
  for (int o = 32; o; o >>= 1) acc += __shfl_down(acc, o, 64);
  __shared__ float red[4];
  if ((t & 63) == 0) red[t >> 6] = acc;
  __syncthreads();
  float inv = 1.0f / (red[0] + red[1] + red[2] + red[3]);
#pragma unroll
  for (int j = 0; j < 4; ++j) {
    int i = t + j * 256;
    if (i < KV) P[row * KV + i] = f2bf(e[j] * inv);
  }
}

// ---------- host ----------
extern "C" void kernel_launch(void* const* d_in, const int* in_sizes, int n_in,
                              void* d_out, int out_size, void* d_ws, size_t ws_size,
                              hipStream_t stream) {
  const float* emb1 = (const float*)d_in[0];
  const float* emb2 = (const float*)d_in[1];
  const float* emb3 = (const float*)d_in[2];
  const float* emb4 = (const float*)d_in[3];
  const float* embA = (const float*)d_in[4];
  const float* Wq1  = (const float*)d_in[5];
  const float* Wq2  = (const float*)d_in[6];
  const float* Wq3  = (const float*)d_in[7];
  const float* Wq4  = (const float*)d_in[8];
  const float* Wk   = (const float*)d_in[9];
  const float* Wv   = (const float*)d_in[10];
  const float* Wo1  = (const float*)d_in[11];
  const float* Wo2  = (const float*)d_in[12];
  const float* Wo3  = (const float*)d_in[13];
  const float* Wo4  = (const float*)d_in[14];
  float* out = (float*)d_out;

  // ---- arena: persistent buffers + one shared scratch region ----
  char* base = (char*)d_ws;
  size_t off = 0;
  auto take = [&](size_t bytes) -> void* {
    void* p = base + off;
    off += (bytes + 255) & ~(size_t)255;
    return p;
  };
  unsigned short* Kt  = (unsigned short*)take(62914560);  // [b,h,o,n] bf16 (persistent)
  unsigned short* Vb  = (unsigned short*)take(62914560);  // [b,h,n,o] bf16 (persistent)
  unsigned short* EB  = (unsigned short*)take(15728640);  // emb1..4 bf16 (persistent)
  unsigned short* WQb = (unsigned short*)take(2785280);   // persistent
  unsigned short* WOb = (unsigned short*)take(696320);    // persistent
  float*          ST  = (float*)take(1024);               // stats: 4 branches * 32 * 2
  char*           scratch = (char*)take(96468992);        // phase A or phase B
  // phase A occupants (dead after K/V GEMMs):
  unsigned short* EA  = (unsigned short*)(scratch);                // 15,728,640 B
  unsigned short* WKb = (unsigned short*)(scratch + 15728640);     //  7,372,800 B
  unsigned short* WVb = (unsigned short*)(scratch + 23101440);     //  7,372,800 B
  // phase B occupants (written only after phase A is consumed):
  unsigned short* QT  = (unsigned short*)(scratch);                // 33,554,432 B
  float*          SC  = (float*)(scratch + 33554432);              // 62,914,560 B
  unsigned short* PR  = QT;                 // probs alias QT (dead after scores GEMM)
  unsigned short* CT  = (unsigned short*)SC;  // ctx^T alias SC (dead after softmax)

  if (ws_size < off) return;  // diagnostic guard: fail with stub-absmax, not a GPU fault

  hipMemsetAsync(ST, 0, 1024, stream);

  // casts
  cast4_kernel<<<4096, 256, 0, stream>>>(embA, 7864320, embA, 0, embA, 0, embA, 0, EA);
  cast4_kernel<<<4096, 256, 0, stream>>>(emb1, 524288, emb2, 1048576, emb3, 2097152, emb4, 4194304, EB);
  cast4_kernel<<<2048, 256, 0, stream>>>(Wk, 3686400, Wk, 0, Wk, 0, Wk, 0, WKb);
  cast4_kernel<<<2048, 256, 0, stream>>>(Wv, 3686400, Wv, 0, Wv, 0, Wv, 0, WVb);
  cast4_kernel<<<1024, 256, 0, stream>>>(Wq1, 16384, Wq2, 65536, Wq3, 262144, Wq4, 1048576, WQb);
  cast4_kernel<<<512, 256, 0, stream>>>(Wo1, 4096, Wo2, 16384, Wo3, 65536, Wo4, 262144, WOb);

  // K^T[b,h,o,n] = Wk[h] @ emb_all[b]^T : M=960,N=1024,K=960
  gemm_nt<0, 0><<<dim3(16, 15, 32), 256, 0, stream>>>(
      WKb, EA, Kt, 960, 1024, 960, 4,
      0L, 960L * 960, 1024L * 960, 0L, 960L * 1024, 1, 0L, 0L, 1.0f, nullptr);
  // V[b,h,n,o] = emb_all[b] @ Wv[h]^T : M=1024,N=960,K=960
  gemm_nt<0, 0><<<dim3(15, 16, 32), 256, 0, stream>>>(
      EA, WVb, Vb, 1024, 960, 960, 4,
      1024L * 960, 0L, 0L, 960L * 960, 1024L * 960, 1, 0L, 0L, 1.0f, nullptr);

  const int  Cs[4]     = {64, 128, 256, 512};
  const long ebOff[4]  = {0, 524288, 1572864, 3670016};
  const long wqOff[4]  = {0, 16384, 81920, 344064};
  const long woOff[4]  = {0, 4096, 20480, 86016};
  const long outOff[4] = {0, 524288, 1572864, 3670016};
  const float kscale = 0.0322748612f;  // 1/sqrt(960)

  for (int i = 0; i < 4; ++i) {
    long C = Cs[i];
    // Q^T[b,h,d,n] = Wq[h] @ emb[b]^T : M=C,N=1024,K=C
    gemm_nt<0, 0><<<dim3(16, C / 64, 32), 256, 0, stream>>>(
        WQb + wqOff[i], EB + ebOff[i], QT, (int)C, 1024, (int)C, 4,
        0L, C * C, 1024L * C, 0L, C * 1024, 1, 0L, 0L, 1.0f, nullptr);
    // scores[bh,c,o] = (Q^T @ K^T^T)/sqrt(KV) : M=C,N=960,K=1024 ; fused stats
    gemm_nt<1, 1><<<dim3(15, C / 64, 32), 256, 0, stream>>>(
        QT, Kt, SC, (int)C, 960, 1024, 1,
        C * 1024, 0L, 960L * 1024, 0L, C * 960, 1, 0L, 0L, kscale, ST + i * 64);
    // instance-norm + softmax -> bf16 probs
    norm_softmax_k<<<dim3(32 * (int)C), 256, 0, stream>>>(
        SC, PR, ST + i * 64, (int)C, 1.0f / (float)(C * 960));
    // ctx^T[b,n,c] = (1/4) sum_h V[b,h] @ probs[b,h]^T : M=1024,N=C,K=960,inner=4
    gemm_nt<0, 0><<<dim3(C / 64, 16, 8), 256, 0, stream>>>(
        Vb, PR, CT, 1024, (int)C, 960, 1,
        4L * 1024 * 960, 0L, 4L * C * 960, 0L, 1024L * C, 4, 1024L * 960, C * 960,
        0.25f, nullptr);
    // out[b,n,c'] = ctx^T[b] @ Wo^T : M=1024,N=C,K=C
    gemm_nt<1, 0><<<dim3(C / 64, 16, 8), 256, 0, stream>>>(
        CT, WOb + woOff[i], out + outOff[i], 1024, (int)C, (int)C, 1,
        1024L * C, 0L, 0L, 0L, 1024L * C, 1, 0L, 0L, 1.0f, nullptr);
  }
  (void)in_sizes; (void)n_in; (void)out_size;
}

// Round 3
// 939.610 us; speedup vs baseline: 1.1806x; 1.1806x over previous
//
#include <hip/hip_runtime.h>
#include <hip/hip_bf16.h>

// ---------- types ----------
typedef __attribute__((ext_vector_type(8))) short short8;
typedef __attribute__((ext_vector_type(4))) float f32x4;

static __device__ __forceinline__ unsigned short f2bf(float x) {
  union { __hip_bfloat16 h; unsigned short u; } cv;
  cv.h = __float2bfloat16(x);
  return cv.u;
}

// ---------- cast fp32 -> bf16, up to 4 concatenated segments ----------
__global__ void cast4_kernel(const float* __restrict__ s0, long n0,
                             const float* __restrict__ s1, long n1,
                             const float* __restrict__ s2, long n2,
                             const float* __restrict__ s3, long n3,
                             unsigned short* __restrict__ dst) {
  long N4 = (n0 + n1 + n2 + n3) >> 2;
  for (long i = blockIdx.x * (long)blockDim.x + threadIdx.x; i < N4;
       i += (long)gridDim.x * blockDim.x) {
    long e = i << 2;
    const float* s; long j = e;
    if (j < n0) s = s0;
    else { j -= n0; if (j < n1) s = s1;
      else { j -= n1; if (j < n2) s = s2;
        else { j -= n2; s = s3; } } }
    float4 v = *reinterpret_cast<const float4*>(s + j);
    ushort4 o;
    o.x = f2bf(v.x); o.y = f2bf(v.y); o.z = f2bf(v.z); o.w = f2bf(v.w);
    *reinterpret_cast<ushort4*>(dst + e) = o;
  }
}

// ---------- generic NT bf16 MFMA GEMM, m97 structure, TMxTN tile ----------
// C[m,n] = alpha * sum_it sum_k A[m,k]*B[n,k].  4 waves, each (TM/2)x(TN/2).
// Staging rows clamped to Mclamp/Nclamp (for padded dims); stores guarded by
// cg<Nwrite; DO_STATS accumulates sum/sumsq over cg<Nvalid into stats[z*2].
template<int TM, int TN, int OUT_F32, int DO_STATS>
__global__ __launch_bounds__(256)
void gemm_nt(const unsigned short* __restrict__ A,
             const unsigned short* __restrict__ B,
             void* __restrict__ Cp,
             int K, int lda, int ldb, long ldc, int Hdiv,
             long sAb, long sAh, long sBb, long sBh, long sC,
             int nInner, long iA, long iB, float alpha,
             float* __restrict__ stats,
             int Mclamp, int Nclamp, int Nwrite, int Nvalid) {
  constexpr int WM = TM / 32, WN = TN / 32;   // 16x16 frags per wave
  __shared__ unsigned short As[TM * 32];
  __shared__ unsigned short Bs[TN * 32];
  __shared__ float red[8];

  int z = blockIdx.z;
  int b = z / Hdiv, h = z % Hdiv;
  const unsigned short* Ab = A + (long)b * sAb + (long)h * sAh;
  const unsigned short* Bb = B + (long)b * sBb + (long)h * sBh;
  int m0 = blockIdx.y * TM, n0 = blockIdx.x * TN;
  int t = threadIdx.x;
  int lane = t & 63, wave = t >> 6;
  int wm = (wave >> 1) * (TM / 2), wn = (wave & 1) * (TN / 2);
  int l15 = lane & 15, q = lane >> 4;
  int arow = t >> 2, acol = (t & 3) * 8;

  int rA[TM / 64], rB[TN / 64];
#pragma unroll
  for (int r = 0; r < TM / 64; ++r) rA[r] = min(m0 + r * 64 + arow, Mclamp - 1);
#pragma unroll
  for (int r = 0; r < TN / 64; ++r) rB[r] = min(n0 + r * 64 + arow, Nclamp - 1);

  f32x4 acc[WM][WN] = {};

  for (int it = 0; it < nInner; ++it) {
    const unsigned short* Ait = Ab + (long)it * iA;
    const unsigned short* Bit = Bb + (long)it * iB;
    for (int k0 = 0; k0 < K; k0 += 32) {
      __syncthreads();  // protect LDS while still being read
#pragma unroll
      for (int r = 0; r < TM / 64; ++r)
        __builtin_amdgcn_global_load_lds(
            (const __attribute__((address_space(1))) void*)(Ait + (long)rA[r] * lda + acol + k0),
            (__attribute__((address_space(3))) void*)(As + r * 2048 + t * 8), 16, 0, 0);
#pragma unroll
      for (int r = 0; r < TN / 64; ++r)
        __builtin_amdgcn_global_load_lds(
            (const __attribute__((address_space(1))) void*)(Bit + (long)rB[r] * ldb + acol + k0),
            (__attribute__((address_space(3))) void*)(Bs + r * 2048 + t * 8), 16, 0, 0);
      __syncthreads();  // drains vmcnt: staged data visible
      short8 af[WM], bfr[WN];
#pragma unroll
      for (int i = 0; i < WM; ++i)
        af[i] = *reinterpret_cast<const short8*>(As + (wm + i * 16 + l15) * 32 + q * 8);
#pragma unroll
      for (int j = 0; j < WN; ++j)
        bfr[j] = *reinterpret_cast<const short8*>(Bs + (wn + j * 16 + l15) * 32 + q * 8);
#pragma unroll
      for (int i = 0; i < WM; ++i)
#pragma unroll
        for (int j = 0; j < WN; ++j)
          acc[i][j] = __builtin_amdgcn_mfma_f32_16x16x32_bf16(af[i], bfr[j], acc[i][j], 0, 0, 0);
    }
  }

  long cbase = (long)z * sC;
  float ssum = 0.f, ssq = 0.f;
#pragma unroll
  for (int i = 0; i < WM; ++i)
#pragma unroll
    for (int j = 0; j < WN; ++j)
#pragma unroll
      for (int r = 0; r < 4; ++r) {
        float v = acc[i][j][r] * alpha;
        int rg = m0 + wm + i * 16 + q * 4 + r;
        int cg = n0 + wn + j * 16 + l15;
        if (cg < Nwrite) {
          long idx = cbase + (long)rg * ldc + cg;
          if (OUT_F32) ((float*)Cp)[idx] = v;
          else ((unsigned short*)Cp)[idx] = f2bf(v);
        }
        if (DO_STATS && cg < Nvalid) { ssum += v; ssq += v * v; }
      }

  if (DO_STATS) {
#pragma unroll
    for (int o = 32; o; o >>= 1) {
      ssum += __shfl_down(ssum, o, 64);
      ssq  += __shfl_down(ssq,  o, 64);
    }
    if (lane == 0) { red[wave] = ssum; red[wave + 4] = ssq; }
    __syncthreads();
    if (t == 0) {
      atomicAdd(stats + (long)z * 2,     red[0] + red[1] + red[2] + red[3]);
      atomicAdd(stats + (long)z * 2 + 1, red[4] + red[5] + red[6] + red[7]);
    }
  }
}

// ---------- instance-norm + softmax over KV=960 (ld 1024), bf16 probs ----------
__global__ __launch_bounds__(256)
void norm_softmax_k(const float* __restrict__ S, unsigned short* __restrict__ P,
                    const float* __restrict__ stats, int C, float invCnt) {
  const int KV = 960, LD = 1024;
  long row = blockIdx.x;            // bh*C + c
  int bh = (int)(row / C);
  const float* s = S + row * LD;
  float m1 = stats[bh * 2 + 0] * invCnt;
  float m2 = stats[bh * 2 + 1] * invCnt;
  float rsig = rsqrtf(m2 - m1 * m1 + 1e-5f);
  int t = threadIdx.x;
  float e[4]; float acc = 0.f;
#pragma unroll
  for (int j = 0; j < 4; ++j) {
    int i = t + j * 256;
    if (i < KV) { e[j] = __expf((s[i] - m1) * rsig); acc += e[j]; }
    else e[j] = 0.f;
  }
#pragma unroll
  for (int o = 32; o; o >>= 1) acc += __shfl_down(acc, o, 64);
  __shared__ float red[4];
  if ((t & 63) == 0) red[t >> 6] = acc;
  __syncthreads();
  float inv = 1.0f / (red[0] + red[1] + red[2] + red[3]);
#pragma unroll
  for (int j = 0; j < 4; ++j) {
    int i = t + j * 256;
    if (i < KV) P[row * LD + i] = f2bf(e[j] * inv);
  }
}

// ---------- host ----------
extern "C" void kernel_launch(void* const* d_in, const int* in_sizes, int n_in,
                              void* d_out, int out_size, void* d_ws, size_t ws_size,
                              hipStream_t stream) {
  const float* emb1 = (const float*)d_in[0];
  const float* emb2 = (const float*)d_in[1];
  const float* emb3 = (const float*)d_in[2];
  const float* emb4 = (const float*)d_in[3];
  const float* embA = (const float*)d_in[4];
  const float* Wq1  = (const float*)d_in[5];
  const float* Wq2  = (const float*)d_in[6];
  const float* Wq3  = (const float*)d_in[7];
  const float* Wq4  = (const float*)d_in[8];
  const float* Wk   = (const float*)d_in[9];
  const float* Wv   = (const float*)d_in[10];
  const float* Wo1  = (const float*)d_in[11];
  const float* Wo2  = (const float*)d_in[12];
  const float* Wo3  = (const float*)d_in[13];
  const float* Wo4  = (const float*)d_in[14];
  float* out = (float*)d_out;

  char* base = (char*)d_ws;
  size_t off = 0;
  auto take = [&](size_t bytes) -> void* {
    void* p = base + off;
    off += (bytes + 255) & ~(size_t)255;
    return p;
  };
  unsigned short* Kt  = (unsigned short*)take(67108864);  // [b,h,1024(o pad),1024(n)]
  unsigned short* Vb  = (unsigned short*)take(62914560);  // [b,h,1024(n),960(o)]
  unsigned short* EB  = (unsigned short*)take(15728640);  // emb1..4 bf16
  unsigned short* WQb = (unsigned short*)take(2785280);
  unsigned short* WOb = (unsigned short*)take(696320);
  float*          ST  = (float*)take(1024);
  char*           scratch = (char*)take(100663296);
  // phase A (dead after K/V GEMMs):
  unsigned short* EA  = (unsigned short*)(scratch);              // 15,728,640
  unsigned short* WKb = (unsigned short*)(scratch + 15728640);   //  7,372,800
  unsigned short* WVb = (unsigned short*)(scratch + 23101440);   //  7,372,800
  // phase B:
  unsigned short* QT  = (unsigned short*)(scratch);              // 33,554,432 [b,h,C,1024]
  float*          SC  = (float*)(scratch + 33554432);            // 67,108,864 [bh,C,1024]
  unsigned short* PR  = QT;                   // probs alias QT
  unsigned short* CT  = (unsigned short*)SC;  // ctx alias SC

  if (ws_size < off) return;  // fail clean (stub absmax) instead of faulting

  hipMemsetAsync(ST, 0, 1024, stream);

  cast4_kernel<<<4096, 256, 0, stream>>>(embA, 7864320, embA, 0, embA, 0, embA, 0, EA);
  cast4_kernel<<<4096, 256, 0, stream>>>(emb1, 524288, emb2, 1048576, emb3, 2097152, emb4, 4194304, EB);
  cast4_kernel<<<2048, 256, 0, stream>>>(Wk, 3686400, Wk, 0, Wk, 0, Wk, 0, WKb);
  cast4_kernel<<<2048, 256, 0, stream>>>(Wv, 3686400, Wv, 0, Wv, 0, Wv, 0, WVb);
  cast4_kernel<<<1024, 256, 0, stream>>>(Wq1, 16384, Wq2, 65536, Wq3, 262144, Wq4, 1048576, WQb);
  cast4_kernel<<<512, 256, 0, stream>>>(Wo1, 4096, Wo2, 16384, Wo3, 65536, Wo4, 262144, WOb);

  // Kt[b,h,o,n] = Wk[h] @ embA[b]^T : M=1024(pad,o clamp 960), N=1024, K=960
  gemm_nt<128, 128, 0, 0><<<dim3(8, 8, 32), 256, 0, stream>>>(
      WKb, EA, Kt, 960, 960, 960, 1024, 4,
      0L, 960L * 960, 1024L * 960, 0L, 1024L * 1024,
      1, 0L, 0L, 1.0f, nullptr, 960, 1024, 1024, 0);
  // Vb[b,h,n,o] = embA[b] @ Wv[h]^T : M=1024, N=1024(pad, write<960), K=960
  gemm_nt<128, 128, 0, 0><<<dim3(8, 8, 32), 256, 0, stream>>>(
      EA, WVb, Vb, 960, 960, 960, 960, 4,
      1024L * 960, 0L, 0L, 960L * 960, 1024L * 960,
      1, 0L, 0L, 1.0f, nullptr, 1024, 960, 960, 0);

  const int  Cs[4]     = {64, 128, 256, 512};
  const long ebOff[4]  = {0, 524288, 1572864, 3670016};
  const long wqOff[4]  = {0, 16384, 81920, 344064};
  const long woOff[4]  = {0, 4096, 20480, 86016};
  const long outOff[4] = {0, 524288, 1572864, 3670016};
  const float kscale = 0.0322748612f;  // 1/sqrt(960)

  for (int i = 0; i < 4; ++i) {
    long C = Cs[i];
    // QT[b,h,d,n] = Wq[h] @ emb[b]^T : M=C, N=1024, K=C
    if (C == 64)
      gemm_nt<64, 128, 0, 0><<<dim3(8, 1, 32), 256, 0, stream>>>(
          WQb + wqOff[i], EB + ebOff[i], QT, (int)C, (int)C, (int)C, 1024, 4,
          0L, C * C, 1024L * C, 0L, C * 1024, 1, 0L, 0L, 1.0f, nullptr,
          (int)C, 1024, 1024, 0);
    else
      gemm_nt<128, 128, 0, 0><<<dim3(8, C / 128, 32), 256, 0, stream>>>(
          WQb + wqOff[i], EB + ebOff[i], QT, (int)C, (int)C, (int)C, 1024, 4,
          0L, C * C, 1024L * C, 0L, C * 1024, 1, 0L, 0L, 1.0f, nullptr,
          (int)C, 1024, 1024, 0);
    // SC[bh,c,o] = QT·Kt / sqrt(KV) : M=C, N=1024(pad; stats<960), K=1024
    if (C == 64)
      gemm_nt<64, 128, 1, 1><<<dim3(8, 1, 32), 256, 0, stream>>>(
          QT, Kt, SC, 1024, 1024, 1024, 1024, 4,
          4L * C * 1024, C * 1024, 4L * 1024 * 1024, 1024L * 1024, C * 1024,
          1, 0L, 0L, kscale, ST + i * 64, (int)C, 1024, 1024, 960);
    else
      gemm_nt<128, 128, 1, 1><<<dim3(8, C / 128, 32), 256, 0, stream>>>(
          QT, Kt, SC, 1024, 1024, 1024, 1024, 4,
          4L * C * 1024, C * 1024, 4L * 1024 * 1024, 1024L * 1024, C * 1024,
          1, 0L, 0L, kscale, ST + i * 64, (int)C, 1024, 1024, 960);
    // instance-norm + softmax -> bf16 probs (ld 1024)
    norm_softmax_k<<<dim3(32 * (int)C), 256, 0, stream>>>(
        SC, PR, ST + i * 64, (int)C, 1.0f / (float)(C * 960));
    // CT[b,n,c] = (1/4) sum_h Vb[b,h] @ PR[b,h]^T : M=1024, N=C, K=960
    if (C == 64)
      gemm_nt<128, 64, 0, 0><<<dim3(1, 8, 8), 256, 0, stream>>>(
          Vb, PR, CT, 960, 960, 1024, C, 1,
          4L * 1024 * 960, 0L, 4L * C * 1024, 0L, 1024L * C,
          4, 1024L * 960, C * 1024, 0.25f, nullptr, 1024, (int)C, (int)C, 0);
    else
      gemm_nt<128, 128, 0, 0><<<dim3(C / 128, 8, 8), 256, 0, stream>>>(
          Vb, PR, CT, 960, 960, 1024, C, 1,
          4L * 1024 * 960, 0L, 4L * C * 1024, 0L, 1024L * C,
          4, 1024L * 960, C * 1024, 0.25f, nullptr, 1024, (int)C, (int)C, 0);
    // out[b,n,c'] = CT[b] @ Wo^T : M=1024, N=C, K=C
    if (C == 64)
      gemm_nt<128, 64, 1, 0><<<dim3(1, 8, 8), 256, 0, stream>>>(
          CT, WOb + woOff[i], out + outOff[i], (int)C, (int)C, (int)C, C, 1,
          1024L * C, 0L, 0L, 0L, 1024L * C,
          1, 0L, 0L, 1.0f, nullptr, 1024, (int)C, (int)C, 0);
    else
      gemm_nt<128, 128, 1, 0><<<dim3(C / 128, 8, 8), 256, 0, stream>>>(
          CT, WOb + woOff[i], out + outOff[i], (int)C, (int)C, (int)C, C, 1,
          1024L * C, 0L, 0L, 0L, 1024L * C,
          1, 0L, 0L, 1.0f, nullptr, 1024, (int)C, (int)C, 0);
  }
  (void)in_sizes; (void)n_in; (void)out_size;
}

// Round 4
// 703.586 us; speedup vs baseline: 1.5767x; 1.3355x over previous
//
#include <hip/hip_runtime.h>
#include <hip/hip_bf16.h>

// ---------- types ----------
typedef __attribute__((ext_vector_type(8))) short short8;
typedef __attribute__((ext_vector_type(4))) float f32x4;

static __device__ __forceinline__ unsigned short f2bf(float x) {
  union { __hip_bfloat16 h; unsigned short u; } cv;
  cv.h = __float2bfloat16(x);
  return cv.u;
}

// ---------- cast fp32 -> bf16, up to 4 concatenated segments ----------
__global__ void cast4_kernel(const float* __restrict__ s0, long n0,
                             const float* __restrict__ s1, long n1,
                             const float* __restrict__ s2, long n2,
                             const float* __restrict__ s3, long n3,
                             unsigned short* __restrict__ dst) {
  long N4 = (n0 + n1 + n2 + n3) >> 2;
  for (long i = blockIdx.x * (long)blockDim.x + threadIdx.x; i < N4;
       i += (long)gridDim.x * blockDim.x) {
    long e = i << 2;
    const float* s; long j = e;
    if (j < n0) s = s0;
    else { j -= n0; if (j < n1) s = s1;
      else { j -= n1; if (j < n2) s = s2;
        else { j -= n2; s = s3; } } }
    float4 v = *reinterpret_cast<const float4*>(s + j);
    ushort4 o;
    o.x = f2bf(v.x); o.y = f2bf(v.y); o.z = f2bf(v.z); o.w = f2bf(v.w);
    *reinterpret_cast<ushort4*>(dst + e) = o;
  }
}

// ---------- generic NT bf16 MFMA GEMM, m97 structure, TMxTN tile ----------
// OUT: 0=bf16, 1=fp32, 2=fp16. Staging rows clamped to Mclamp/Nclamp; stores
// guarded by cg<Nwrite; DO_STATS accumulates sum/sumsq over cg<Nvalid.
template<int TM, int TN, int OUT, int DO_STATS>
__global__ __launch_bounds__(256)
void gemm_nt(const unsigned short* __restrict__ A,
             const unsigned short* __restrict__ B,
             void* __restrict__ Cp,
             int K, int lda, int ldb, long ldc, int Hdiv,
             long sAb, long sAh, long sBb, long sBh, long sC,
             int nInner, long iA, long iB, float alpha,
             float* __restrict__ stats,
             int Mclamp, int Nclamp, int Nwrite, int Nvalid) {
  constexpr int WM = TM / 32, WN = TN / 32;
  __shared__ unsigned short As[TM * 32];
  __shared__ unsigned short Bs[TN * 32];
  __shared__ float red[8];

  int z = blockIdx.z;
  int b = z / Hdiv, h = z % Hdiv;
  const unsigned short* Ab = A + (long)b * sAb + (long)h * sAh;
  const unsigned short* Bb = B + (long)b * sBb + (long)h * sBh;
  int m0 = blockIdx.y * TM, n0 = blockIdx.x * TN;
  int t = threadIdx.x;
  int lane = t & 63, wave = t >> 6;
  int wm = (wave >> 1) * (TM / 2), wn = (wave & 1) * (TN / 2);
  int l15 = lane & 15, q = lane >> 4;
  int arow = t >> 2, acol = (t & 3) * 8;

  int rA[TM / 64], rB[TN / 64];
#pragma unroll
  for (int r = 0; r < TM / 64; ++r) rA[r] = min(m0 + r * 64 + arow, Mclamp - 1);
#pragma unroll
  for (int r = 0; r < TN / 64; ++r) rB[r] = min(n0 + r * 64 + arow, Nclamp - 1);

  f32x4 acc[WM][WN] = {};

  for (int it = 0; it < nInner; ++it) {
    const unsigned short* Ait = Ab + (long)it * iA;
    const unsigned short* Bit = Bb + (long)it * iB;
    for (int k0 = 0; k0 < K; k0 += 32) {
      __syncthreads();
#pragma unroll
      for (int r = 0; r < TM / 64; ++r)
        __builtin_amdgcn_global_load_lds(
            (const __attribute__((address_space(1))) void*)(Ait + (long)rA[r] * lda + acol + k0),
            (__attribute__((address_space(3))) void*)(As + r * 2048 + t * 8), 16, 0, 0);
#pragma unroll
      for (int r = 0; r < TN / 64; ++r)
        __builtin_amdgcn_global_load_lds(
            (const __attribute__((address_space(1))) void*)(Bit + (long)rB[r] * ldb + acol + k0),
            (__attribute__((address_space(3))) void*)(Bs + r * 2048 + t * 8), 16, 0, 0);
      __syncthreads();
      short8 af[WM], bfr[WN];
#pragma unroll
      for (int i = 0; i < WM; ++i)
        af[i] = *reinterpret_cast<const short8*>(As + (wm + i * 16 + l15) * 32 + q * 8);
#pragma unroll
      for (int j = 0; j < WN; ++j)
        bfr[j] = *reinterpret_cast<const short8*>(Bs + (wn + j * 16 + l15) * 32 + q * 8);
#pragma unroll
      for (int i = 0; i < WM; ++i)
#pragma unroll
        for (int j = 0; j < WN; ++j)
          acc[i][j] = __builtin_amdgcn_mfma_f32_16x16x32_bf16(af[i], bfr[j], acc[i][j], 0, 0, 0);
    }
  }

  long cbase = (long)z * sC;
  float ssum = 0.f, ssq = 0.f;
#pragma unroll
  for (int i = 0; i < WM; ++i)
#pragma unroll
    for (int j = 0; j < WN; ++j)
#pragma unroll
      for (int r = 0; r < 4; ++r) {
        float v = acc[i][j][r] * alpha;
        int rg = m0 + wm + i * 16 + q * 4 + r;
        int cg = n0 + wn + j * 16 + l15;
        if (cg < Nwrite) {
          long idx = cbase + (long)rg * ldc + cg;
          if (OUT == 1) ((float*)Cp)[idx] = v;
          else if (OUT == 2) ((_Float16*)Cp)[idx] = (_Float16)v;
          else ((unsigned short*)Cp)[idx] = f2bf(v);
        }
        if (DO_STATS && cg < Nvalid) { ssum += v; ssq += v * v; }
      }

  if (DO_STATS) {
#pragma unroll
    for (int o = 32; o; o >>= 1) {
      ssum += __shfl_down(ssum, o, 64);
      ssq  += __shfl_down(ssq,  o, 64);
    }
    if (lane == 0) { red[wave] = ssum; red[wave + 4] = ssq; }
    __syncthreads();
    if (t == 0) {
      atomicAdd(stats + (long)z * 2,     red[0] + red[1] + red[2] + red[3]);
      atomicAdd(stats + (long)z * 2 + 1, red[4] + red[5] + red[6] + red[7]);
    }
  }
}

// ---------- 4-branch batched NT GEMM (128x128), branch from blockIdx.x ----------
struct MDesc {
  long aOff[4], bOff[4], cOff[4];
  long sAz[4], sBz[4], sCz[4];
  long iA[4], iB[4];
  int  lda[4], ldb[4], ldcv[4];
  int  Kk[4], Ncl[4], nIn[4];
  int  nstart[4];
  float alpha[4];
};

template<int OUT_F32>
__global__ __launch_bounds__(256)
void gemm_multi(const unsigned short* __restrict__ A0,
                const unsigned short* __restrict__ B0,
                void* __restrict__ Cp, MDesc d) {
  __shared__ unsigned short As[128 * 32];
  __shared__ unsigned short Bs[128 * 32];
  int bx = blockIdx.x;
  int br = (bx >= d.nstart[3]) ? 3 : (bx >= d.nstart[2]) ? 2 : (bx >= d.nstart[1]) ? 1 : 0;
  int z = blockIdx.z;
  int n0 = (bx - d.nstart[br]) * 128;
  int m0 = blockIdx.y * 128;
  int K = d.Kk[br], lda = d.lda[br], ldb = d.ldb[br], ldc = d.ldcv[br];
  int Ncl = d.Ncl[br], nInner = d.nIn[br];
  float alpha = d.alpha[br];
  const unsigned short* Ab = A0 + d.aOff[br] + (long)z * d.sAz[br];
  const unsigned short* Bb = B0 + d.bOff[br] + (long)z * d.sBz[br];

  int t = threadIdx.x, lane = t & 63, wave = t >> 6;
  int wm = (wave >> 1) * 64, wn = (wave & 1) * 64;
  int l15 = lane & 15, q = lane >> 4;
  int arow = t >> 2, acol = (t & 3) * 8;
  int rA0 = m0 + arow, rA1 = m0 + 64 + arow;
  int rB0 = min(n0 + arow, Ncl - 1), rB1 = min(n0 + 64 + arow, Ncl - 1);

  f32x4 acc[4][4] = {};
  for (int it = 0; it < nInner; ++it) {
    const unsigned short* Ait = Ab + (long)it * d.iA[br];
    const unsigned short* Bit = Bb + (long)it * d.iB[br];
    for (int k0 = 0; k0 < K; k0 += 32) {
      __syncthreads();
      __builtin_amdgcn_global_load_lds(
          (const __attribute__((address_space(1))) void*)(Ait + (long)rA0 * lda + acol + k0),
          (__attribute__((address_space(3))) void*)(As + t * 8), 16, 0, 0);
      __builtin_amdgcn_global_load_lds(
          (const __attribute__((address_space(1))) void*)(Ait + (long)rA1 * lda + acol + k0),
          (__attribute__((address_space(3))) void*)(As + 2048 + t * 8), 16, 0, 0);
      __builtin_amdgcn_global_load_lds(
          (const __attribute__((address_space(1))) void*)(Bit + (long)rB0 * ldb + acol + k0),
          (__attribute__((address_space(3))) void*)(Bs + t * 8), 16, 0, 0);
      __builtin_amdgcn_global_load_lds(
          (const __attribute__((address_space(1))) void*)(Bit + (long)rB1 * ldb + acol + k0),
          (__attribute__((address_space(3))) void*)(Bs + 2048 + t * 8), 16, 0, 0);
      __syncthreads();
      short8 af[4], bfr[4];
#pragma unroll
      for (int i = 0; i < 4; ++i)
        af[i] = *reinterpret_cast<const short8*>(As + (wm + i * 16 + l15) * 32 + q * 8);
#pragma unroll
      for (int j = 0; j < 4; ++j)
        bfr[j] = *reinterpret_cast<const short8*>(Bs + (wn + j * 16 + l15) * 32 + q * 8);
#pragma unroll
      for (int i = 0; i < 4; ++i)
#pragma unroll
        for (int j = 0; j < 4; ++j)
          acc[i][j] = __builtin_amdgcn_mfma_f32_16x16x32_bf16(af[i], bfr[j], acc[i][j], 0, 0, 0);
    }
  }

  long cb = d.cOff[br] + (long)z * d.sCz[br];
#pragma unroll
  for (int i = 0; i < 4; ++i)
#pragma unroll
    for (int j = 0; j < 4; ++j)
#pragma unroll
      for (int r = 0; r < 4; ++r) {
        float v = acc[i][j][r] * alpha;
        int rg = m0 + wm + i * 16 + q * 4 + r;
        int cg = n0 + wn + j * 16 + l15;
        if (cg < Ncl) {
          long idx = cb + (long)rg * ldc + cg;
          if (OUT_F32) ((float*)Cp)[idx] = v;
          else ((unsigned short*)Cp)[idx] = f2bf(v);
        }
      }
}

// ---------- instance-norm + softmax over KV=960 (fp16 in, ld 1024), bf16 out ----------
__global__ __launch_bounds__(256)
void norm_softmax_k(const _Float16* __restrict__ S, unsigned short* __restrict__ P,
                    const float* __restrict__ stats, int C, float invCnt) {
  const int KV = 960, LD = 1024;
  long row = blockIdx.x;            // bh*C + c
  int bh = (int)(row / C);
  const _Float16* s = S + row * LD;
  float m1 = stats[bh * 2 + 0] * invCnt;
  float m2 = stats[bh * 2 + 1] * invCnt;
  float rsig = rsqrtf(m2 - m1 * m1 + 1e-5f);
  int t = threadIdx.x;
  float e[4]; float acc = 0.f;
#pragma unroll
  for (int j = 0; j < 4; ++j) {
    int i = t + j * 256;
    if (i < KV) { e[j] = __expf(((float)s[i] - m1) * rsig); acc += e[j]; }
    else e[j] = 0.f;
  }
#pragma unroll
  for (int o = 32; o; o >>= 1) acc += __shfl_down(acc, o, 64);
  __shared__ float red[4];
  if ((t & 63) == 0) red[t >> 6] = acc;
  __syncthreads();
  float inv = 1.0f / (red[0] + red[1] + red[2] + red[3]);
#pragma unroll
  for (int j = 0; j < 4; ++j) {
    int i = t + j * 256;
    if (i < KV) P[row * LD + i] = f2bf(e[j] * inv);
  }
}

// ---------- host ----------
extern "C" void kernel_launch(void* const* d_in, const int* in_sizes, int n_in,
                              void* d_out, int out_size, void* d_ws, size_t ws_size,
                              hipStream_t stream) {
  const float* emb1 = (const float*)d_in[0];
  const float* emb2 = (const float*)d_in[1];
  const float* emb3 = (const float*)d_in[2];
  const float* emb4 = (const float*)d_in[3];
  const float* embA = (const float*)d_in[4];
  const float* Wq1  = (const float*)d_in[5];
  const float* Wq2  = (const float*)d_in[6];
  const float* Wq3  = (const float*)d_in[7];
  const float* Wq4  = (const float*)d_in[8];
  const float* Wk   = (const float*)d_in[9];
  const float* Wv   = (const float*)d_in[10];
  float* out = (float*)d_out;

  char* base = (char*)d_ws;
  size_t off = 0;
  auto take = [&](size_t bytes) -> void* {
    void* p = base + off;
    off += (bytes + 255) & ~(size_t)255;
    return p;
  };
  unsigned short* Kt  = (unsigned short*)take(67108864);  // [b,h,1024(o pad),1024]; CT_all aliases later
  unsigned short* Vb  = (unsigned short*)take(62914560);  // [b,h,1024,960]
  unsigned short* EB  = (unsigned short*)take(15728640);  // emb1..4 bf16
  unsigned short* WQb = (unsigned short*)take(2785280);
  unsigned short* WOb = (unsigned short*)take(696320);
  float*          ST  = (float*)take(1024);
  unsigned short* QTa = (unsigned short*)take(62914560);  // QT_all / PR_all (probs in place)
  char*           scratch = (char*)take(33554432);        // phase A casts OR per-branch fp16 scores
  unsigned short* EA  = (unsigned short*)(scratch);              // 15,728,640
  unsigned short* WKb = (unsigned short*)(scratch + 15728640);   //  7,372,800
  unsigned short* WVb = (unsigned short*)(scratch + 23101440);   //  7,372,800 (contiguous after WKb)
  _Float16*       SC  = (_Float16*)(scratch);                    // per-branch scores, max 33.5 MB
  unsigned short* CT  = Kt;   // ctx output aliases Kt (dead after last scores GEMM)

  if (ws_size < off) return;  // fail clean instead of faulting

  hipMemsetAsync(ST, 0, 1024, stream);

  // casts (5 launches)
  cast4_kernel<<<4096, 256, 0, stream>>>(embA, 7864320, embA, 0, embA, 0, embA, 0, EA);
  cast4_kernel<<<4096, 256, 0, stream>>>(emb1, 524288, emb2, 1048576, emb3, 2097152, emb4, 4194304, EB);
  cast4_kernel<<<2048, 256, 0, stream>>>(Wk, 3686400, Wv, 3686400, Wk, 0, Wk, 0, WKb);
  cast4_kernel<<<1024, 256, 0, stream>>>(Wq1, 16384, Wq2, 65536, Wq3, 262144, Wq4, 1048576, WQb);
  cast4_kernel<<<512, 256, 0, stream>>>((const float*)d_in[11], 4096, (const float*)d_in[12], 16384,
                                        (const float*)d_in[13], 65536, (const float*)d_in[14], 262144, WOb);

  // Kt[b,h,o,n] = Wk[h] @ embA[b]^T : M=1024(pad, clamp 960), N=1024, K=960
  gemm_nt<128, 128, 0, 0><<<dim3(8, 8, 32), 256, 0, stream>>>(
      WKb, EA, Kt, 960, 960, 960, 1024, 4,
      0L, 960L * 960, 1024L * 960, 0L, 1024L * 1024,
      1, 0L, 0L, 1.0f, nullptr, 960, 1024, 1024, 0);
  // Vb[b,h,n,o] = embA[b] @ Wv[h]^T : M=1024, N=1024(pad, write<960), K=960
  gemm_nt<128, 128, 0, 0><<<dim3(8, 8, 32), 256, 0, stream>>>(
      EA, WVb, Vb, 960, 960, 960, 960, 4,
      1024L * 960, 0L, 0L, 960L * 960, 1024L * 960,
      1, 0L, 0L, 1.0f, nullptr, 1024, 960, 960, 0);

  const long Cs[4]     = {64, 128, 256, 512};
  const long ebOff[4]  = {0, 524288, 1572864, 3670016};
  const long wqOff[4]  = {0, 16384, 81920, 344064};
  const long woOff[4]  = {0, 4096, 20480, 86016};
  const long outOff[4] = {0, 524288, 1572864, 3670016};
  const long qtOff[4]  = {0, 2097152, 6291456, 14680064};  // elems into QTa
  const float kscale = 0.0322748612f;  // 1/sqrt(960)

  // Q_i: QT[b,h,d,n] = Wq[h] @ emb[b]^T : M=C, N=1024, K=C  (4 launches)
  for (int i = 0; i < 4; ++i) {
    long C = Cs[i];
    if (C == 64)
      gemm_nt<64, 128, 0, 0><<<dim3(8, 1, 32), 256, 0, stream>>>(
          WQb + wqOff[i], EB + ebOff[i], QTa + qtOff[i], (int)C, (int)C, (int)C, 1024, 4,
          0L, C * C, 1024L * C, 0L, C * 1024, 1, 0L, 0L, 1.0f, nullptr,
          (int)C, 1024, 1024, 0);
    else
      gemm_nt<128, 128, 0, 0><<<dim3(8, C / 128, 32), 256, 0, stream>>>(
          WQb + wqOff[i], EB + ebOff[i], QTa + qtOff[i], (int)C, (int)C, (int)C, 1024, 4,
          0L, C * C, 1024L * C, 0L, C * 1024, 1, 0L, 0L, 1.0f, nullptr,
          (int)C, 1024, 1024, 0);
  }

  // scores_i (fp16 out + stats) then softmax_i (probs in place into QT slot)
  for (int i = 0; i < 4; ++i) {
    long C = Cs[i];
    if (C == 64)
      gemm_nt<64, 128, 2, 1><<<dim3(8, 1, 32), 256, 0, stream>>>(
          QTa + qtOff[i], Kt, SC, 1024, 1024, 1024, 1024, 4,
          4L * C * 1024, C * 1024, 4L * 1024 * 1024, 1024L * 1024, C * 1024,
          1, 0L, 0L, kscale, ST + i * 64, (int)C, 1024, 1024, 960);
    else
      gemm_nt<128, 128, 2, 1><<<dim3(8, C / 128, 32), 256, 0, stream>>>(
          QTa + qtOff[i], Kt, SC, 1024, 1024, 1024, 1024, 4,
          4L * C * 1024, C * 1024, 4L * 1024 * 1024, 1024L * 1024, C * 1024,
          1, 0L, 0L, kscale, ST + i * 64, (int)C, 1024, 1024, 960);
    norm_softmax_k<<<dim3(32 * (int)C), 256, 0, stream>>>(
        SC, QTa + qtOff[i], ST + i * 64, (int)C, 1.0f / (float)(C * 960));
  }

  // ctx-all: CT[b,n,c] = (1/4) sum_h Vb[b,h] @ PR[b,h]^T, all branches, one launch
  {
    MDesc d;
    for (int i = 0; i < 4; ++i) {
      long C = Cs[i];
      d.aOff[i] = 0;            d.sAz[i] = 4L * 1024 * 960;  d.iA[i] = 1024L * 960;
      d.bOff[i] = qtOff[i];     d.sBz[i] = 4L * C * 1024;    d.iB[i] = C * 1024;
      d.cOff[i] = outOff[i];    d.sCz[i] = 1024L * C;
      d.lda[i] = 960; d.ldb[i] = 1024; d.ldcv[i] = (int)C;
      d.Kk[i] = 960; d.Ncl[i] = (int)C; d.nIn[i] = 4;
      d.alpha[i] = 0.25f;
    }
    d.nstart[0] = 0; d.nstart[1] = 1; d.nstart[2] = 2; d.nstart[3] = 4;  // ceil(C/128) cum
    gemm_multi<0><<<dim3(8, 8, 8), 256, 0, stream>>>(Vb, QTa, CT, d);
  }

  // out-all: out[b,n,c'] = CT[b] @ Wo^T, all branches, one launch
  {
    MDesc d;
    for (int i = 0; i < 4; ++i) {
      long C = Cs[i];
      d.aOff[i] = outOff[i];    d.sAz[i] = 1024L * C;        d.iA[i] = 0;
      d.bOff[i] = woOff[i];     d.sBz[i] = 0;                d.iB[i] = 0;
      d.cOff[i] = outOff[i];    d.sCz[i] = 1024L * C;
      d.lda[i] = (int)C; d.ldb[i] = (int)C; d.ldcv[i] = (int)C;
      d.Kk[i] = (int)C; d.Ncl[i] = (int)C; d.nIn[i] = 1;
      d.alpha[i] = 1.0f;
    }
    d.nstart[0] = 0; d.nstart[1] = 1; d.nstart[2] = 2; d.nstart[3] = 4;
    gemm_multi<1><<<dim3(8, 8, 8), 256, 0, stream>>>(CT, WOb, out, d);
  }
  (void)in_sizes; (void)n_in; (void)out_size;
}